// Round 1
// baseline (97.645 us; speedup 1.0000x reference)
//
#include <hip/hip_runtime.h>

// OnlineAverager: sliding-window online mean.
// UPDATE=4096, BATCH=256, NUM_UPD=16, SNAPSHOT=65536, SNAP_LEN=1110016.
//
// Key identities:
//  - snap position p (block b=p>>12) is touched by steps i in [b-15, b] ∩ [0,255]
//  - the update element used at step i for position p is update_flat[p + i*61440]
//    (each update element read exactly once)
//  - norm weight at step i for position p is 16-(b-i) = s+1 where s = i-(b-15)
//  - d_out[p] = final snap[p] for p < SNAP_LEN (output chunk + new_snapshot head
//    are contiguous); d_out[SNAP_LEN..2158592)=0; d_out[2158592] = idx0+256.

#define UPDATE_SIZE   4096
#define BATCH         256
#define NUM_UPD       16
#define SNAPSHOT_SIZE (UPDATE_SIZE * NUM_UPD)           // 65536
#define OUT_SIZE      (UPDATE_SIZE * BATCH)             // 1048576
#define SNAP_LEN      (SNAPSHOT_SIZE + (BATCH - 1) * UPDATE_SIZE) // 1110016
#define STRIDE        (SNAPSHOT_SIZE - UPDATE_SIZE)     // 61440

#define MAIN_T  (SNAP_LEN / 4)          // 277504 threads, one float4 each
#define ZERO_T  (OUT_SIZE / 4)          // 262144 threads zero-fill the tail
#define TOTAL_T (MAIN_T + ZERO_T)       // 539648 -> exactly 2108 blocks of 256

__global__ __launch_bounds__(256) void online_avg_kernel(
    const float* __restrict__ upd,      // (256, 65536) flat
    const float* __restrict__ snap_in,  // (SNAP_LEN,)
    const float* __restrict__ uidx,     // (1,)
    float* __restrict__ out) {          // (2158593,)
  const int t = blockIdx.x * 256 + threadIdx.x;

  if (t < MAIN_T) {
    const int p = t * 4;
    const int b = p >> 12;              // 0..270, wave-uniform (4096 % 256 == 0)
    const float idx0 = uidx[0];

    float4 acc = *reinterpret_cast<const float4*>(snap_in + p);

#pragma unroll
    for (int s = 0; s < 16; ++s) {
      const int i  = b - 15 + s;        // step index, ascending
      const int ic = min(max(i, 0), 255);                 // clamp for safe load
      const float4 x = *reinterpret_cast<const float4*>(upd + p + ic * STRIDE);
      // weight = clip(norm, 0, idx0+i+1); norm here = s+1 (compile-time)
      const float w  = fminf((float)(s + 1), idx0 + (float)(i + 1));
      const float rw = (i == ic) ? (1.0f / w) : 0.0f;     // mask invalid steps
      acc.x = fmaf(x.x - acc.x, rw, acc.x);
      acc.y = fmaf(x.y - acc.y, rw, acc.y);
      acc.z = fmaf(x.z - acc.z, rw, acc.z);
      acc.w = fmaf(x.w - acc.w, rw, acc.w);
    }

    *reinterpret_cast<float4*>(out + p) = acc;
    if (t == 0) out[OUT_SIZE + SNAP_LEN] = idx0 + (float)BATCH;  // update_idx out
  } else if (t < TOTAL_T) {
    const int q = (t - MAIN_T) * 4;
    *reinterpret_cast<float4*>(out + SNAP_LEN + q) =
        make_float4(0.0f, 0.0f, 0.0f, 0.0f);
  }
}

extern "C" void kernel_launch(void* const* d_in, const int* in_sizes, int n_in,
                              void* d_out, int out_size, void* d_ws, size_t ws_size,
                              hipStream_t stream) {
  const float* upd     = (const float*)d_in[0];
  const float* snap_in = (const float*)d_in[1];
  const float* uidx    = (const float*)d_in[2];
  float* out           = (float*)d_out;

  const int blocks = TOTAL_T / 256;     // 2108 exactly
  online_avg_kernel<<<blocks, 256, 0, stream>>>(upd, snap_in, uidx, out);
}